// Round 5
// baseline (42.989 us; speedup 1.0000x reference)
//
#include <hip/hip_runtime.h>
#include <stdint.h>

// SpikeFP32Sqrt — R4.
// R3 post-mortem: 42.8 us = 6.12 TB/s over 262MB cold traffic = 97% of the
// measured copy ceiling (6.29 TB/s) IF the input is re-fetched; but R1's
// profiled FETCH=65MB suggests ~196MB real traffic (4.6 TB/s -> headroom).
// R4 tests the latency/MLP hypothesis: 2 rows per lane, all 16 dwordx4 loads
// issued before compute (16KB/wave in flight vs 8KB), two independent sqrt
// chains (2x compute ILP), 16 nt-stores. Neutral result => BW wall => roofline.

typedef float vfloat4 __attribute__((ext_vector_type(4)));

__device__ __forceinline__ uint32_t nibrev(uint32_t x) {
    // reverse the 8 nibbles of x (slot k -> slot 7-k)
    x = __builtin_bswap32(x);
    return ((x & 0x0F0F0F0Fu) << 4) | ((x >> 4) & 0x0F0F0F0Fu);
}

__device__ __forceinline__ uint32_t xpose8(uint32_t A, int l7) {
    // 8x8 nibble transpose across an 8-lane group:
    // out[lane c].slot j = in[lane j].slot c   (slots are LSB-first nibbles)
    {
        uint32_t o = (uint32_t)__shfl_xor((int)A, 1);
        A = (l7 & 1) ? ((A & 0xF0F0F0F0u) | ((o >> 4) & 0x0F0F0F0Fu))
                     : ((A & 0x0F0F0F0Fu) | ((o & 0x0F0F0F0Fu) << 4));
    }
    {
        uint32_t o = (uint32_t)__shfl_xor((int)A, 2);
        A = (l7 & 2) ? ((A & 0xFF00FF00u) | ((o >> 8) & 0x00FF00FFu))
                     : ((A & 0x00FF00FFu) | ((o & 0x00FF00FFu) << 8));
    }
    {
        uint32_t o = (uint32_t)__shfl_xor((int)A, 4);
        A = (l7 & 4) ? ((A & 0xFFFF0000u) | (o >> 16))
                     : ((A & 0x0000FFFFu) | (o << 16));
    }
    return A;
}

__device__ __forceinline__ uint32_t nib_of(vfloat4 v) {
    return ((uint32_t)(v.x != 0.0f) << 3) |
           ((uint32_t)(v.y != 0.0f) << 2) |
           ((uint32_t)(v.z != 0.0f) << 1) |
            (uint32_t)(v.w != 0.0f);
}

__device__ __forceinline__ uint32_t sqrt_word(uint32_t w) {
    // integer transcription of the reference's gate-level sqrt (verified R0)
    uint32_t s = w >> 31;
    uint32_t E = (w >> 23) & 0xFFu;
    uint32_t M = w & 0x7FFFFFu;

    bool e_all_one = (E == 0xFFu);
    bool e_is_zero = (E == 0u);
    bool m_is_zero = (M == 0u);
    bool is_zero = e_is_zero && m_is_zero;
    bool is_inf  = e_all_one && m_is_zero;
    bool is_nan  = e_all_one && !m_is_zero;
    bool is_neg  = (s != 0u) && !is_zero;

    uint32_t e_even = ((E & 1u) == 0u);                // ref's "exp_is_odd"
    uint32_t addc   = e_even ? 126u : 127u;
    uint32_t Er     = ((E + addc) & 0x1FFu) >> 1;

    uint32_t mant24 = M | 0x800000u;
    uint32_t rad25  = e_even ? (mant24 << 1) : mant24;

    uint64_t rad = (uint64_t)rad25 << 25;
    uint32_t rem = 0, q = 0;
#pragma unroll
    for (int i = 24; i >= 0; --i) {
        rem = (rem << 2) | (uint32_t)((rad >> (2 * i)) & 3ull);
        uint32_t t = (q << 2) | 1u;
        if (rem >= t) { rem -= t; q = (q << 1) | 1u; }
        else          {           q = (q << 1);      }
    }

    uint32_t round_bit  = q & 1u;
    uint32_t mant23     = (q >> 1) & 0x7FFFFFu;
    uint32_t lsb        = mant23 & 1u;
    uint32_t sticky     = (rem != 0u);
    uint32_t round_up   = round_bit & (sticky | lsb);
    uint32_t mant_final = (mant23 + round_up) & 0x7FFFFFu;

    uint32_t res = (Er << 23) | mant_final;
    if (is_nan || is_neg) res = 0x7FC00000u;
    if (is_zero)          res = 0u;
    if (is_inf)           res = 0x7F800000u;
    return res;
}

__global__ __launch_bounds__(256) void spike_sqrt_kernel(const float* __restrict__ x,
                                                         float* __restrict__ out,
                                                         int nrows) {
    const int lane = threadIdx.x & 63;
    const int l7 = lane & 7;
    const int waveInBlock = threadIdx.x >> 6;
    const size_t gw = (size_t)blockIdx.x * 4 + waveInBlock;   // global wave id
    const size_t baseRow = gw * 128;                          // 128 rows per wave
    if (baseRow >= (size_t)nrows) return;

    const vfloat4* __restrict__ xt = reinterpret_cast<const vfloat4*>(x) + baseRow * 8;

    // ---- issue all 16 coalesced loads up-front (16KB/wave in flight) ----
    vfloat4 va[8], vb[8];
#pragma unroll
    for (int j = 0; j < 8; ++j) va[j] = xt[j * 64 + lane];
#pragma unroll
    for (int j = 0; j < 8; ++j) vb[j] = xt[(j + 8) * 64 + lane];

    // ---- pack round-j nibble into slot j, transpose per 64-row set ------
    uint32_t A = 0, B = 0;
#pragma unroll
    for (int j = 0; j < 8; ++j) A |= nib_of(va[j]) << (4 * j);
#pragma unroll
    for (int j = 0; j < 8; ++j) B |= nib_of(vb[j]) << (4 * j);

    uint32_t w0 = nibrev(xpose8(A, l7));   // row baseRow      + 8*(l&7)+(l>>3)
    uint32_t w1 = nibrev(xpose8(B, l7));   // row baseRow + 64 + 8*(l&7)+(l>>3)

    // ---- two independent sqrt chains (2x ILP) ---------------------------
    uint32_t res0 = sqrt_word(w0);
    uint32_t res1 = sqrt_word(w1);

    // ---- inverse transform + coalesced non-temporal stores --------------
    uint32_t V0 = xpose8(nibrev(res0), l7);
    uint32_t V1 = xpose8(nibrev(res1), l7);
    vfloat4* __restrict__ ot = reinterpret_cast<vfloat4*>(out) + baseRow * 8;
#pragma unroll
    for (int j = 0; j < 8; ++j) {
        uint32_t nib = (V0 >> (4 * j)) & 0xFu;
        vfloat4 v;
        v.x = (float)((nib >> 3) & 1u);
        v.y = (float)((nib >> 2) & 1u);
        v.z = (float)((nib >> 1) & 1u);
        v.w = (float)(nib & 1u);
        __builtin_nontemporal_store(v, &ot[j * 64 + lane]);
    }
#pragma unroll
    for (int j = 0; j < 8; ++j) {
        uint32_t nib = (V1 >> (4 * j)) & 0xFu;
        vfloat4 v;
        v.x = (float)((nib >> 3) & 1u);
        v.y = (float)((nib >> 2) & 1u);
        v.z = (float)((nib >> 1) & 1u);
        v.w = (float)(nib & 1u);
        __builtin_nontemporal_store(v, &ot[(j + 8) * 64 + lane]);
    }
}

extern "C" void kernel_launch(void* const* d_in, const int* in_sizes, int n_in,
                              void* d_out, int out_size, void* d_ws, size_t ws_size,
                              hipStream_t stream) {
    const float* x = (const float*)d_in[0];
    float* out = (float*)d_out;
    int nrows = in_sizes[0] / 32;       // 1048576
    int rowsPerBlock = 512;             // 4 waves * 128 rows
    int grid = (nrows + rowsPerBlock - 1) / rowsPerBlock;
    spike_sqrt_kernel<<<grid, 256, 0, stream>>>(x, out, nrows);
}